// Round 16
// baseline (95.661 us; speedup 1.0000x reference)
//
#include <hip/hip_runtime.h>

#define NTYPES 216
#define NPIX   4096
#define KD     576      // C*3*3
#define ROWLEN 577      // KD + bias
#define NPC    32       // pixels per block-iteration
#define PSTR   640      // u16 elements per LDS row (576 data + 64 shift pad)

typedef __attribute__((ext_vector_type(8))) short short8;
typedef __attribute__((ext_vector_type(4))) float f32x4;
typedef __attribute__((ext_vector_type(4), aligned(4))) float f32x4u;  // 4B-aligned
typedef __attribute__((ext_vector_type(8))) unsigned short u16x8;
typedef __attribute__((ext_vector_type(4))) unsigned short u16x4;
typedef __attribute__((ext_vector_type(2))) unsigned short u16x2;

static __device__ __forceinline__ unsigned short f2bf(float f) {
    unsigned u = __builtin_bit_cast(unsigned, f);
    unsigned r = (u + 0x7FFFu + ((u >> 16) & 1u)) >> 16;  // RNE
    return (unsigned short)r;
}

// ---------- Kernel A ----------
// blocks 0..511 : grouped 3x3 conv + bias + relu -> hbf in HWC layout (pixel*64+c)
// block  512    : counting-sort pixels by bucket (parallel scan)
__global__ __launch_bounds__(256) void prep_kernel(
        const float* __restrict__ x, const float* __restrict__ w1,
        const float* __restrict__ b1, const int* __restrict__ buckets,
        unsigned short* __restrict__ hbf, int* __restrict__ offsets,
        int* __restrict__ sorted) {
    int tid = threadIdx.x;
    if (blockIdx.x == 512) {
        // ---- counting sort with parallel scan ----
        __shared__ int cnt[256];
        __shared__ int pre[256];
        cnt[tid] = 0;
        __syncthreads();
        for (int i = tid; i < NPIX; i += 256) atomicAdd(&cnt[buckets[i]], 1);
        __syncthreads();
        int v = cnt[tid];
        pre[tid] = v;
        __syncthreads();
        #pragma unroll
        for (int s = 1; s < 256; s <<= 1) {
            int add = (tid >= s) ? pre[tid - s] : 0;
            __syncthreads();
            pre[tid] += add;
            __syncthreads();
        }
        int excl = pre[tid] - v;            // exclusive prefix
        if (tid <= NTYPES) offsets[tid] = excl;
        cnt[tid] = excl;
        __syncthreads();
        for (int i = tid; i < NPIX; i += 256) {
            int b = buckets[i];
            sorted[atomicAdd(&cnt[b], 1)] = i;
        }
        return;
    }
    // ---- body1: thread = (pixel, och-pair); HWC write (128B contiguous per pixel) ----
    int px_g = blockIdx.x * 8 + (tid >> 5);   // pixel 0..4095
    int op   = tid & 31;                       // och pair 0..31
    int oc   = op * 2;
    int py = px_g >> 6, pxx = px_g & 63;
    int g = oc >> 4;
    const float* w1a = w1 + oc * 144;
    const float* w1b = w1a + 144;
    float a0 = b1[oc], a1 = b1[oc + 1];
    #pragma unroll
    for (int ci = 0; ci < 16; ++ci) {
        const float* xp = x + (g * 16 + ci) * 4096;
        #pragma unroll
        for (int dy = 0; dy < 3; ++dy) {
            int yy = py + dy - 1;
            bool yok = (yy >= 0 && yy < 64);
            #pragma unroll
            for (int dx = 0; dx < 3; ++dx) {
                int xx = pxx + dx - 1;
                float xv = (yok && xx >= 0 && xx < 64) ? xp[yy * 64 + xx] : 0.f;
                int wi = ci * 9 + dy * 3 + dx;
                a0 = fmaf(xv, w1a[wi], a0);
                a1 = fmaf(xv, w1b[wi], a1);
            }
        }
    }
    u16x2 r2;
    r2[0] = f2bf(fmaxf(a0, 0.f));
    r2[1] = f2bf(fmaxf(a1, 0.f));
    *(u16x2*)&hbf[px_g * 64 + oc] = r2;
}

// ---------- Kernel B: per-bucket MFMA GEMM; pos-major K; coalesced HWC gather ----------
__global__ __launch_bounds__(512) void dyn_kernel(
        const unsigned short* __restrict__ hbf, const float* __restrict__ emb,
        const float* __restrict__ w2, const float* __restrict__ b2,
        const float* __restrict__ x, const int* __restrict__ offsets,
        const int* __restrict__ sorted, float* __restrict__ out) {

    __shared__ alignas(16) unsigned short Wl[64 * PSTR];   // 80 KB  filter tile (bf16, pos-major)
    __shared__ alignas(16) unsigned short Pl[NPC * PSTR];  // 40 KB  patches (bf16, pos-major)
    __shared__ alignas(16) unsigned short Dl[NPC * 72];    //  4.5 KB intermediate
    __shared__ alignas(16) unsigned short w2l[64 * 72];    //  9 KB  1x1 weights bf16
    __shared__ float bias_l[64];
    __shared__ int pixs[NPC];

    int t = blockIdx.x;
    int start = offsets[t];
    int n = offsets[t + 1] - start;
    if (n <= 0) return;

    int tid  = threadIdx.x;
    int lane = tid & 63;
    int wv   = tid >> 6;
    int m    = wv & 3;          // M-tile (16 out channels)
    int ph   = wv >> 2;         // pixel half
    int ra   = lane & 15;
    int kg   = lane >> 4;

    const float* eb = emb + (size_t)t * 36928;

    // ---- W stage: coalesced f32 loads; scatter u16 into pos-major columns ----
    #pragma unroll
    for (int it = 0; it < 9; ++it) {
        int u  = tid + it * 512;
        int r  = u / 72;
        int c0 = (u - r * 72) * 8;
        const float* src = eb + r * ROWLEN + c0;
        f32x4u a = *(const f32x4u*)src;
        f32x4u b = *(const f32x4u*)(src + 4);
        unsigned short* wrow = &Wl[r * PSTR + (r & 7) * 8];
        #pragma unroll
        for (int j = 0; j < 8; ++j) {
            int c = c0 + j;
            int cch = c / 9, pos = c - cch * 9;
            float val = (j < 4) ? a[j] : b[j - 4];
            wrow[pos * 64 + cch] = f2bf(val);
        }
    }
    if (tid < 64) bias_l[tid] = eb[tid * ROWLEN + KD];

    // stage w2 -> bf16 LDS (once)
    {
        int o = tid >> 3, i8 = (tid & 7) * 8;
        const float* src = w2 + o * 64 + i8;
        u16x8 v;
        #pragma unroll
        for (int j = 0; j < 8; ++j) v[j] = f2bf(src[j]);
        *(u16x8*)&w2l[o * 72 + i8] = v;
    }
    __syncthreads();   // W / w2 / bias ready

    int rowW = m * 16 + ra;
    const unsigned short* pA = Wl + rowW * PSTR + (rowW & 7) * 8 + kg * 8;
    int ob0 = m * 16 + kg * 4;
    float bias0 = bias_l[ob0 + 0], bias1 = bias_l[ob0 + 1];
    float bias2 = bias_l[ob0 + 2], bias3 = bias_l[ob0 + 3];

    const unsigned short* pB = Pl + (ph * 16 + ra) * PSTR + (ra & 7) * 8 + kg * 8;

    // gather roles: 16 threads per pixel slot, each loads 8B per position
    int gp = tid >> 4;          // pixel 0..31
    int gk = tid & 15;          // channel-quad 0..15 (gk*4 channels)
    unsigned short* pdst = Pl + gp * PSTR + (gp & 7) * 8;

    for (int base = 0; base < n; base += NPC) {
        __syncthreads();   // protect pixs/Pl/Dl from previous iteration's readers
        if (tid < NPC) pixs[tid] = (base + tid < n) ? sorted[start + base + tid] : -1;
        __syncthreads();

        // ---- stage patch tile P[32 px][9 pos * 64 ch] from HWC hbf (coalesced) ----
        {
            int pixel = pixs[gp];
            int py = pixel >> 6, px = pixel & 63;
            #pragma unroll
            for (int dy = 0; dy < 3; ++dy) {
                int yy = py + dy - 1;
                bool yok = (yy >= 0 && yy < 64);
                #pragma unroll
                for (int dx = 0; dx < 3; ++dx) {
                    int pos = dy * 3 + dx;
                    int xx = px + dx - 1;
                    u16x4 v = {0, 0, 0, 0};
                    if (pixel >= 0 && yok && xx >= 0 && xx < 64)
                        v = *(const u16x4*)&hbf[(yy * 64 + xx) * 64 + gk * 4];
                    *(u16x4*)(pdst + pos * 64 + gk * 4) = v;
                }
            }
        }
        __syncthreads();   // P ready

        // ---- K-loop: 18 A-reads + 18 B-reads from LDS + 18 MFMA ----
        f32x4 acc = {0.f, 0.f, 0.f, 0.f};
        #pragma unroll
        for (int ck = 0; ck < 9; ++ck) {
            #pragma unroll
            for (int ks = 0; ks < 2; ++ks) {
                u16x8 av = *(const u16x8*)(pA + ck * 64 + ks * 32);
                u16x8 bv = *(const u16x8*)(pB + ck * 64 + ks * 32);
                acc = __builtin_amdgcn_mfma_f32_16x16x32_bf16(
                          __builtin_bit_cast(short8, av),
                          __builtin_bit_cast(short8, bv), acc, 0, 0, 0);
            }
        }

        // ---- bias + relu -> Dl (bf16) ----
        {
            int pi = ph * 16 + ra;
            u16x4 dv;
            dv[0] = f2bf(fmaxf(acc[0] + bias0, 0.f));
            dv[1] = f2bf(fmaxf(acc[1] + bias1, 0.f));
            dv[2] = f2bf(fmaxf(acc[2] + bias2, 0.f));
            dv[3] = f2bf(fmaxf(acc[3] + bias3, 0.f));
            *(u16x4*)&Dl[pi * 72 + ob0] = dv;
        }
        __syncthreads();   // D ready

        // ---- GEMM2: 1x1 conv (K=64) ----
        f32x4 acc2 = {0.f, 0.f, 0.f, 0.f};
        #pragma unroll
        for (int ks = 0; ks < 2; ++ks) {
            u16x8 a2  = *(const u16x8*)&w2l[(m * 16 + ra) * 72 + ks * 32 + kg * 8];
            u16x8 b2v = *(const u16x8*)&Dl[(ph * 16 + ra) * 72 + ks * 32 + kg * 8];
            acc2 = __builtin_amdgcn_mfma_f32_16x16x32_bf16(
                       __builtin_bit_cast(short8, a2),
                       __builtin_bit_cast(short8, b2v), acc2, 0, 0, 0);
        }

        // ---- epilogue: + b2 + residual, relu, store ----
        {
            int pi = ph * 16 + ra;
            int pixel = pixs[pi];
            if (pixel >= 0) {
                #pragma unroll
                for (int j = 0; j < 4; ++j) {
                    int o = ob0 + j;
                    float v = acc2[j] + b2[o] + x[o * 4096 + pixel];
                    out[o * 4096 + pixel] = fmaxf(v, 0.f);
                }
            }
        }
    }
}

extern "C" void kernel_launch(void* const* d_in, const int* in_sizes, int n_in,
                              void* d_out, int out_size, void* d_ws, size_t ws_size,
                              hipStream_t stream) {
    const float* x       = (const float*)d_in[0];
    const int*   buckets = (const int*)d_in[1];
    const float* w1      = (const float*)d_in[2];
    const float* b1      = (const float*)d_in[3];
    const float* emb     = (const float*)d_in[4];
    const float* w2      = (const float*)d_in[5];
    const float* b2      = (const float*)d_in[6];
    float* out = (float*)d_out;

    char* ws = (char*)d_ws;
    unsigned short* hbf = (unsigned short*)ws;              // 512 KB (HWC)
    int*   offsets      = (int*)(ws + (1 << 20));           // 217 ints
    int*   sorted       = (int*)(ws + (1 << 20) + 4096);    // 4096 ints

    prep_kernel<<<513, 256, 0, stream>>>(x, w1, b1, buckets, hbf, offsets, sorted);
    dyn_kernel<<<NTYPES, 512, 0, stream>>>(hbf, emb, w2, b2, x, offsets, sorted, out);
}

// Round 17
// 33.922 us; speedup vs baseline: 2.8200x; 2.8200x over previous
//
#include <hip/hip_runtime.h>

#define NTYPES 216
#define NPIX   4096
#define KD     576      // C*3*3
#define ROWLEN 577      // KD + bias
#define NPC    32       // pixels per block-iteration
#define PSTR   640      // u16 elements per LDS row (576 data + 64 shift pad)

typedef __attribute__((ext_vector_type(8))) short short8;
typedef __attribute__((ext_vector_type(4))) float f32x4;
typedef __attribute__((ext_vector_type(4), aligned(4))) float f32x4u;  // 4B-aligned
typedef __attribute__((ext_vector_type(8))) unsigned short u16x8;
typedef __attribute__((ext_vector_type(4))) unsigned short u16x4;

static __device__ __forceinline__ unsigned short f2bf(float f) {
    unsigned u = __builtin_bit_cast(unsigned, f);
    unsigned r = (u + 0x7FFFu + ((u >> 16) & 1u)) >> 16;  // RNE
    return (unsigned short)r;
}

// ---------- Kernel A: blocks 0..255 grouped conv (CHW compute, HWC store); block 256 sort ----------
__global__ __launch_bounds__(256) void prep_kernel(
        const float* __restrict__ x, const float* __restrict__ w1,
        const float* __restrict__ b1, const int* __restrict__ buckets,
        unsigned short* __restrict__ hbf, int* __restrict__ offsets,
        int* __restrict__ sorted) {
    int tid = threadIdx.x;
    if (blockIdx.x == 256) {
        // ---- counting sort with parallel scan ----
        __shared__ int cnt[256];
        __shared__ int pre[256];
        cnt[tid] = 0;
        __syncthreads();
        for (int i = tid; i < NPIX; i += 256) atomicAdd(&cnt[buckets[i]], 1);
        __syncthreads();
        int v = cnt[tid];
        pre[tid] = v;
        __syncthreads();
        #pragma unroll
        for (int s = 1; s < 256; s <<= 1) {
            int add = (tid >= s) ? pre[tid - s] : 0;
            __syncthreads();
            pre[tid] += add;
            __syncthreads();
        }
        int excl = pre[tid] - v;            // exclusive prefix
        if (tid <= NTYPES) offsets[tid] = excl;
        cnt[tid] = excl;
        __syncthreads();
        for (int i = tid; i < NPIX; i += 256) {
            int b = buckets[i];
            sorted[atomicAdd(&cnt[b], 1)] = i;
        }
        return;
    }
    // ---- body1: grouped conv, 4 px/thread (c block-uniform), HWC scatter store ----
    int flat = blockIdx.x * 256 + tid;   // c(6) | y(6) | x4(4)
    int x4 = flat & 15;
    int y  = (flat >> 4) & 63;
    int c  = flat >> 10;                  // block-uniform
    int g  = c >> 4;
    const float* wrow = w1 + c * 144;
    float o0, o1, o2, o3;
    o0 = o1 = o2 = o3 = b1[c];
    #pragma unroll
    for (int ci = 0; ci < 16; ++ci) {
        const float* xp = x + (g * 16 + ci) * 4096;
        #pragma unroll
        for (int dy = 0; dy < 3; ++dy) {
            int yy = y + dy - 1;
            if (yy < 0 || yy > 63) continue;
            const float* row = xp + yy * 64 + x4 * 4;
            f32x4 mm = *(const f32x4*)row;
            float xl = (x4 > 0)  ? row[-1] : 0.f;
            float xr = (x4 < 15) ? row[4]  : 0.f;
            float wa = wrow[ci * 9 + dy * 3 + 0];
            float wb = wrow[ci * 9 + dy * 3 + 1];
            float wc = wrow[ci * 9 + dy * 3 + 2];
            o0 = fmaf(wa, xl,    fmaf(wb, mm[0], fmaf(wc, mm[1], o0)));
            o1 = fmaf(wa, mm[0], fmaf(wb, mm[1], fmaf(wc, mm[2], o1)));
            o2 = fmaf(wa, mm[1], fmaf(wb, mm[2], fmaf(wc, mm[3], o2)));
            o3 = fmaf(wa, mm[2], fmaf(wb, mm[3], fmaf(wc, xr,    o3)));
        }
    }
    // HWC store: hbf[pixel*64 + c], 4 scattered u16 stores (fire-and-forget)
    int pix0 = y * 64 + x4 * 4;
    hbf[(pix0 + 0) * 64 + c] = f2bf(fmaxf(o0, 0.f));
    hbf[(pix0 + 1) * 64 + c] = f2bf(fmaxf(o1, 0.f));
    hbf[(pix0 + 2) * 64 + c] = f2bf(fmaxf(o2, 0.f));
    hbf[(pix0 + 3) * 64 + c] = f2bf(fmaxf(o3, 0.f));
}

// ---------- Kernel B: per-bucket MFMA GEMM; pos-major K; coalesced HWC gather ----------
__global__ __launch_bounds__(512) void dyn_kernel(
        const unsigned short* __restrict__ hbf, const float* __restrict__ emb,
        const float* __restrict__ w2, const float* __restrict__ b2,
        const float* __restrict__ x, const int* __restrict__ offsets,
        const int* __restrict__ sorted, float* __restrict__ out) {

    __shared__ alignas(16) unsigned short Wl[64 * PSTR];   // 80 KB  filter tile (bf16, pos-major)
    __shared__ alignas(16) unsigned short Pl[NPC * PSTR];  // 40 KB  patches (bf16, pos-major)
    __shared__ alignas(16) unsigned short Dl[NPC * 72];    //  4.5 KB intermediate
    __shared__ alignas(16) unsigned short w2l[64 * 72];    //  9 KB  1x1 weights bf16
    __shared__ float bias_l[64];
    __shared__ int pixs[NPC];

    int t = blockIdx.x;
    int start = offsets[t];
    int n = offsets[t + 1] - start;
    if (n <= 0) return;

    int tid  = threadIdx.x;
    int lane = tid & 63;
    int wv   = tid >> 6;
    int m    = wv & 3;          // M-tile (16 out channels)
    int ph   = wv >> 2;         // pixel half
    int ra   = lane & 15;
    int kg   = lane >> 4;

    const float* eb = emb + (size_t)t * 36928;

    // ---- W stage: coalesced f32 loads; scatter u16 into pos-major columns ----
    #pragma unroll
    for (int it = 0; it < 9; ++it) {
        int u  = tid + it * 512;
        int r  = u / 72;
        int c0 = (u - r * 72) * 8;
        const float* src = eb + r * ROWLEN + c0;
        f32x4u a = *(const f32x4u*)src;
        f32x4u b = *(const f32x4u*)(src + 4);
        unsigned short* wrow = &Wl[r * PSTR + (r & 7) * 8];
        #pragma unroll
        for (int j = 0; j < 8; ++j) {
            int c = c0 + j;
            int cch = c / 9, pos = c - cch * 9;
            float val = (j < 4) ? a[j] : b[j - 4];
            wrow[pos * 64 + cch] = f2bf(val);
        }
    }
    if (tid < 64) bias_l[tid] = eb[tid * ROWLEN + KD];

    // stage w2 -> bf16 LDS (once)
    {
        int o = tid >> 3, i8 = (tid & 7) * 8;
        const float* src = w2 + o * 64 + i8;
        u16x8 v;
        #pragma unroll
        for (int j = 0; j < 8; ++j) v[j] = f2bf(src[j]);
        *(u16x8*)&w2l[o * 72 + i8] = v;
    }
    __syncthreads();   // W / w2 / bias ready

    int rowW = m * 16 + ra;
    const unsigned short* pA = Wl + rowW * PSTR + (rowW & 7) * 8 + kg * 8;
    int ob0 = m * 16 + kg * 4;
    float bias0 = bias_l[ob0 + 0], bias1 = bias_l[ob0 + 1];
    float bias2 = bias_l[ob0 + 2], bias3 = bias_l[ob0 + 3];

    const unsigned short* pB = Pl + (ph * 16 + ra) * PSTR + (ra & 7) * 8 + kg * 8;

    // gather roles: 16 threads per pixel slot, each loads 8B per position
    int gp = tid >> 4;          // pixel 0..31
    int gk = tid & 15;          // channel-quad 0..15 (gk*4 channels)
    unsigned short* pdst = Pl + gp * PSTR + (gp & 7) * 8;

    for (int base = 0; base < n; base += NPC) {
        __syncthreads();   // protect pixs/Pl/Dl from previous iteration's readers
        if (tid < NPC) pixs[tid] = (base + tid < n) ? sorted[start + base + tid] : -1;
        __syncthreads();

        // ---- stage patch tile P[32 px][9 pos * 64 ch] from HWC hbf (coalesced) ----
        {
            int pixel = pixs[gp];
            int py = pixel >> 6, px = pixel & 63;
            #pragma unroll
            for (int dy = 0; dy < 3; ++dy) {
                int yy = py + dy - 1;
                bool yok = (yy >= 0 && yy < 64);
                #pragma unroll
                for (int dx = 0; dx < 3; ++dx) {
                    int pos = dy * 3 + dx;
                    int xx = px + dx - 1;
                    u16x4 v = {0, 0, 0, 0};
                    if (pixel >= 0 && yok && xx >= 0 && xx < 64)
                        v = *(const u16x4*)&hbf[(yy * 64 + xx) * 64 + gk * 4];
                    *(u16x4*)(pdst + pos * 64 + gk * 4) = v;
                }
            }
        }
        __syncthreads();   // P ready

        // ---- K-loop: 18 A-reads + 18 B-reads from LDS + 18 MFMA ----
        f32x4 acc = {0.f, 0.f, 0.f, 0.f};
        #pragma unroll
        for (int ck = 0; ck < 9; ++ck) {
            #pragma unroll
            for (int ks = 0; ks < 2; ++ks) {
                u16x8 av = *(const u16x8*)(pA + ck * 64 + ks * 32);
                u16x8 bv = *(const u16x8*)(pB + ck * 64 + ks * 32);
                acc = __builtin_amdgcn_mfma_f32_16x16x32_bf16(
                          __builtin_bit_cast(short8, av),
                          __builtin_bit_cast(short8, bv), acc, 0, 0, 0);
            }
        }

        // ---- bias + relu -> Dl (bf16) ----
        {
            int pi = ph * 16 + ra;
            u16x4 dv;
            dv[0] = f2bf(fmaxf(acc[0] + bias0, 0.f));
            dv[1] = f2bf(fmaxf(acc[1] + bias1, 0.f));
            dv[2] = f2bf(fmaxf(acc[2] + bias2, 0.f));
            dv[3] = f2bf(fmaxf(acc[3] + bias3, 0.f));
            *(u16x4*)&Dl[pi * 72 + ob0] = dv;
        }
        __syncthreads();   // D ready

        // ---- GEMM2: 1x1 conv (K=64) ----
        f32x4 acc2 = {0.f, 0.f, 0.f, 0.f};
        #pragma unroll
        for (int ks = 0; ks < 2; ++ks) {
            u16x8 a2  = *(const u16x8*)&w2l[(m * 16 + ra) * 72 + ks * 32 + kg * 8];
            u16x8 b2v = *(const u16x8*)&Dl[(ph * 16 + ra) * 72 + ks * 32 + kg * 8];
            acc2 = __builtin_amdgcn_mfma_f32_16x16x32_bf16(
                       __builtin_bit_cast(short8, a2),
                       __builtin_bit_cast(short8, b2v), acc2, 0, 0, 0);
        }

        // ---- epilogue: + b2 + residual, relu, store ----
        {
            int pi = ph * 16 + ra;
            int pixel = pixs[pi];
            if (pixel >= 0) {
                #pragma unroll
                for (int j = 0; j < 4; ++j) {
                    int o = ob0 + j;
                    float v = acc2[j] + b2[o] + x[o * 4096 + pixel];
                    out[o * 4096 + pixel] = fmaxf(v, 0.f);
                }
            }
        }
    }
}

extern "C" void kernel_launch(void* const* d_in, const int* in_sizes, int n_in,
                              void* d_out, int out_size, void* d_ws, size_t ws_size,
                              hipStream_t stream) {
    const float* x       = (const float*)d_in[0];
    const int*   buckets = (const int*)d_in[1];
    const float* w1      = (const float*)d_in[2];
    const float* b1      = (const float*)d_in[3];
    const float* emb     = (const float*)d_in[4];
    const float* w2      = (const float*)d_in[5];
    const float* b2      = (const float*)d_in[6];
    float* out = (float*)d_out;

    char* ws = (char*)d_ws;
    unsigned short* hbf = (unsigned short*)ws;              // 512 KB (HWC)
    int*   offsets      = (int*)(ws + (1 << 20));           // 217 ints
    int*   sorted       = (int*)(ws + (1 << 20) + 4096);    // 4096 ints

    prep_kernel<<<257, 256, 0, stream>>>(x, w1, b1, buckets, hbf, offsets, sorted);
    dyn_kernel<<<NTYPES, 512, 0, stream>>>(hbf, emb, w2, b2, x, offsets, sorted, out);
}

// Round 18
// 31.169 us; speedup vs baseline: 3.0691x; 1.0883x over previous
//
#include <hip/hip_runtime.h>

#define NTYPES 216
#define NPIX   4096
#define KD     576      // C*3*3
#define ROWLEN 577      // KD + bias
#define NPC    32       // pixels per block-iteration
#define PSTR   640      // u16 elements per LDS row (576 data + 64 shift pad)

typedef __attribute__((ext_vector_type(8))) short short8;
typedef __attribute__((ext_vector_type(4))) float f32x4;
typedef __attribute__((ext_vector_type(4), aligned(4))) float f32x4u;  // 4B-aligned
typedef __attribute__((ext_vector_type(8))) unsigned short u16x8;
typedef __attribute__((ext_vector_type(4))) unsigned short u16x4;

static __device__ __forceinline__ unsigned short f2bf(float f) {
    unsigned u = __builtin_bit_cast(unsigned, f);
    unsigned r = (u + 0x7FFFu + ((u >> 16) & 1u)) >> 16;  // RNE
    return (unsigned short)r;
}

// ---------- Kernel A: blocks 0..255 grouped conv (CHW compute, HWC store); block 256 sort ----------
__global__ __launch_bounds__(256) void prep_kernel(
        const float* __restrict__ x, const float* __restrict__ w1,
        const float* __restrict__ b1, const int* __restrict__ buckets,
        unsigned short* __restrict__ hbf, int* __restrict__ offsets,
        int* __restrict__ sorted) {
    int tid = threadIdx.x;
    if (blockIdx.x == 256) {
        // ---- counting sort with parallel scan ----
        __shared__ int cnt[256];
        __shared__ int pre[256];
        cnt[tid] = 0;
        __syncthreads();
        for (int i = tid; i < NPIX; i += 256) atomicAdd(&cnt[buckets[i]], 1);
        __syncthreads();
        int v = cnt[tid];
        pre[tid] = v;
        __syncthreads();
        #pragma unroll
        for (int s = 1; s < 256; s <<= 1) {
            int add = (tid >= s) ? pre[tid - s] : 0;
            __syncthreads();
            pre[tid] += add;
            __syncthreads();
        }
        int excl = pre[tid] - v;            // exclusive prefix
        if (tid <= NTYPES) offsets[tid] = excl;
        cnt[tid] = excl;
        __syncthreads();
        for (int i = tid; i < NPIX; i += 256) {
            int b = buckets[i];
            sorted[atomicAdd(&cnt[b], 1)] = i;
        }
        return;
    }
    // ---- body1: grouped conv, 4 px/thread (c block-uniform), HWC scatter store ----
    int flat = blockIdx.x * 256 + tid;   // c(6) | y(6) | x4(4)
    int x4 = flat & 15;
    int y  = (flat >> 4) & 63;
    int c  = flat >> 10;                  // block-uniform
    int g  = c >> 4;
    const float* wrow = w1 + c * 144;
    float o0, o1, o2, o3;
    o0 = o1 = o2 = o3 = b1[c];
    #pragma unroll
    for (int ci = 0; ci < 16; ++ci) {
        const float* xp = x + (g * 16 + ci) * 4096;
        #pragma unroll
        for (int dy = 0; dy < 3; ++dy) {
            int yy = y + dy - 1;
            if (yy < 0 || yy > 63) continue;
            const float* row = xp + yy * 64 + x4 * 4;
            f32x4 mm = *(const f32x4*)row;
            float xl = (x4 > 0)  ? row[-1] : 0.f;
            float xr = (x4 < 15) ? row[4]  : 0.f;
            float wa = wrow[ci * 9 + dy * 3 + 0];
            float wb = wrow[ci * 9 + dy * 3 + 1];
            float wc = wrow[ci * 9 + dy * 3 + 2];
            o0 = fmaf(wa, xl,    fmaf(wb, mm[0], fmaf(wc, mm[1], o0)));
            o1 = fmaf(wa, mm[0], fmaf(wb, mm[1], fmaf(wc, mm[2], o1)));
            o2 = fmaf(wa, mm[1], fmaf(wb, mm[2], fmaf(wc, mm[3], o2)));
            o3 = fmaf(wa, mm[2], fmaf(wb, mm[3], fmaf(wc, xr,    o3)));
        }
    }
    // HWC store: hbf[pixel*64 + c], 4 scattered u16 stores (fire-and-forget)
    int pix0 = y * 64 + x4 * 4;
    hbf[(pix0 + 0) * 64 + c] = f2bf(fmaxf(o0, 0.f));
    hbf[(pix0 + 1) * 64 + c] = f2bf(fmaxf(o1, 0.f));
    hbf[(pix0 + 2) * 64 + c] = f2bf(fmaxf(o2, 0.f));
    hbf[(pix0 + 3) * 64 + c] = f2bf(fmaxf(o3, 0.f));
}

// ---------- Kernel B: per-bucket MFMA GEMM; P0-gather overlapped with W-stream ----------
__global__ __launch_bounds__(512) void dyn_kernel(
        const unsigned short* __restrict__ hbf, const float* __restrict__ emb,
        const float* __restrict__ w2, const float* __restrict__ b2,
        const float* __restrict__ x, const int* __restrict__ offsets,
        const int* __restrict__ sorted, float* __restrict__ out) {

    __shared__ alignas(16) unsigned short Wl[64 * PSTR];   // 80 KB  filter tile (bf16, pos-major)
    __shared__ alignas(16) unsigned short Pl[NPC * PSTR];  // 40 KB  patches (bf16, pos-major)
    __shared__ alignas(16) unsigned short Dl[NPC * 72];    //  4.5 KB intermediate
    __shared__ alignas(16) unsigned short w2l[64 * 72];    //  9 KB  1x1 weights bf16
    __shared__ float bias_l[64];

    int t = blockIdx.x;
    int start = offsets[t];
    int n = offsets[t + 1] - start;
    if (n <= 0) return;

    int tid  = threadIdx.x;
    int lane = tid & 63;
    int wv   = tid >> 6;
    int m    = wv & 3;          // M-tile (16 out channels)
    int ph   = wv >> 2;         // pixel half
    int ra   = lane & 15;
    int kg   = lane >> 4;

    const float* eb = emb + (size_t)t * 36928;

    // gather roles
    int gp = tid >> 4;          // pixel 0..31
    int gk = tid & 15;          // channel-quad
    unsigned short* pdst = Pl + gp * PSTR + (gp & 7) * 8;

    // ---- P0 gather into registers (issued FIRST; rides under the W-stream) ----
    int pixel0 = (gp < n) ? sorted[start + gp] : -1;
    u16x4 p0[9];
    {
        int py = pixel0 >> 6, px = pixel0 & 63;
        #pragma unroll
        for (int dy = 0; dy < 3; ++dy) {
            int yy = py + dy - 1;
            bool yok = (yy >= 0 && yy < 64);
            #pragma unroll
            for (int dx = 0; dx < 3; ++dx) {
                int pos = dy * 3 + dx;
                int xx = px + dx - 1;
                u16x4 v = {0, 0, 0, 0};
                if (pixel0 >= 0 && yok && xx >= 0 && xx < 64)
                    v = *(const u16x4*)&hbf[(yy * 64 + xx) * 64 + gk * 4];
                p0[pos] = v;
            }
        }
    }

    // ---- W stage: coalesced f32 loads; scatter u16 into pos-major columns ----
    #pragma unroll
    for (int it = 0; it < 9; ++it) {
        int u  = tid + it * 512;
        int r  = u / 72;
        int c0 = (u - r * 72) * 8;
        const float* src = eb + r * ROWLEN + c0;
        f32x4u a = *(const f32x4u*)src;
        f32x4u b = *(const f32x4u*)(src + 4);
        unsigned short* wrow = &Wl[r * PSTR + (r & 7) * 8];
        #pragma unroll
        for (int j = 0; j < 8; ++j) {
            int c = c0 + j;
            int cch = c / 9, pos = c - cch * 9;
            float val = (j < 4) ? a[j] : b[j - 4];
            wrow[pos * 64 + cch] = f2bf(val);
        }
    }
    if (tid < 64) bias_l[tid] = eb[tid * ROWLEN + KD];

    // stage w2 -> bf16 LDS (once)
    {
        int o = tid >> 3, i8 = (tid & 7) * 8;
        const float* src = w2 + o * 64 + i8;
        u16x8 v;
        #pragma unroll
        for (int j = 0; j < 8; ++j) v[j] = f2bf(src[j]);
        *(u16x8*)&w2l[o * 72 + i8] = v;
    }

    // ---- write P0 regs to Pl ----
    #pragma unroll
    for (int pos = 0; pos < 9; ++pos)
        *(u16x4*)(pdst + pos * 64 + gk * 4) = p0[pos];

    __syncthreads();   // W / P0 / w2 / bias all ready

    int rowW = m * 16 + ra;
    const unsigned short* pA = Wl + rowW * PSTR + (rowW & 7) * 8 + kg * 8;
    int ob0 = m * 16 + kg * 4;
    float bias0 = bias_l[ob0 + 0], bias1 = bias_l[ob0 + 1];
    float bias2 = bias_l[ob0 + 2], bias3 = bias_l[ob0 + 3];
    const unsigned short* pB = Pl + (ph * 16 + ra) * PSTR + (ra & 7) * 8 + kg * 8;

    for (int base = 0; base < n; base += NPC) {
        if (base > 0) {
            // rare tail (P(n>32) ~ 0.3%): gather directly to Pl
            // safe: previous D-ready barrier guarantees all waves done reading Pl
            int pixel = (base + gp < n) ? sorted[start + base + gp] : -1;
            int py = pixel >> 6, px = pixel & 63;
            #pragma unroll
            for (int dy = 0; dy < 3; ++dy) {
                int yy = py + dy - 1;
                bool yok = (yy >= 0 && yy < 64);
                #pragma unroll
                for (int dx = 0; dx < 3; ++dx) {
                    int pos = dy * 3 + dx;
                    int xx = px + dx - 1;
                    u16x4 v = {0, 0, 0, 0};
                    if (pixel >= 0 && yok && xx >= 0 && xx < 64)
                        v = *(const u16x4*)&hbf[(yy * 64 + xx) * 64 + gk * 4];
                    *(u16x4*)(pdst + pos * 64 + gk * 4) = v;
                }
            }
            __syncthreads();   // P ready (also separates Dl overwrite from prev GEMM2 reads)
        }

        // ---- K-loop: 18 A-reads + 18 B-reads from LDS + 18 MFMA ----
        f32x4 acc = {0.f, 0.f, 0.f, 0.f};
        #pragma unroll
        for (int ck = 0; ck < 9; ++ck) {
            #pragma unroll
            for (int ks = 0; ks < 2; ++ks) {
                u16x8 av = *(const u16x8*)(pA + ck * 64 + ks * 32);
                u16x8 bv = *(const u16x8*)(pB + ck * 64 + ks * 32);
                acc = __builtin_amdgcn_mfma_f32_16x16x32_bf16(
                          __builtin_bit_cast(short8, av),
                          __builtin_bit_cast(short8, bv), acc, 0, 0, 0);
            }
        }

        // ---- bias + relu -> Dl (bf16) ----
        {
            int pi = ph * 16 + ra;
            u16x4 dv;
            dv[0] = f2bf(fmaxf(acc[0] + bias0, 0.f));
            dv[1] = f2bf(fmaxf(acc[1] + bias1, 0.f));
            dv[2] = f2bf(fmaxf(acc[2] + bias2, 0.f));
            dv[3] = f2bf(fmaxf(acc[3] + bias3, 0.f));
            *(u16x4*)&Dl[pi * 72 + ob0] = dv;
        }
        __syncthreads();   // D ready (all waves done reading Pl for this iter)

        // ---- GEMM2: 1x1 conv (K=64) ----
        f32x4 acc2 = {0.f, 0.f, 0.f, 0.f};
        #pragma unroll
        for (int ks = 0; ks < 2; ++ks) {
            u16x8 a2  = *(const u16x8*)&w2l[(m * 16 + ra) * 72 + ks * 32 + kg * 8];
            u16x8 b2v = *(const u16x8*)&Dl[(ph * 16 + ra) * 72 + ks * 32 + kg * 8];
            acc2 = __builtin_amdgcn_mfma_f32_16x16x32_bf16(
                       __builtin_bit_cast(short8, a2),
                       __builtin_bit_cast(short8, b2v), acc2, 0, 0, 0);
        }

        // ---- epilogue: + b2 + residual, relu, store ----
        {
            int pi = ph * 16 + ra;
            int pixel = (base + pi < n) ? sorted[start + base + pi] : -1;
            if (pixel >= 0) {
                #pragma unroll
                for (int j = 0; j < 4; ++j) {
                    int o = ob0 + j;
                    float v = acc2[j] + b2[o] + x[o * 4096 + pixel];
                    out[o * 4096 + pixel] = fmaxf(v, 0.f);
                }
            }
        }
    }
}

extern "C" void kernel_launch(void* const* d_in, const int* in_sizes, int n_in,
                              void* d_out, int out_size, void* d_ws, size_t ws_size,
                              hipStream_t stream) {
    const float* x       = (const float*)d_in[0];
    const int*   buckets = (const int*)d_in[1];
    const float* w1      = (const float*)d_in[2];
    const float* b1      = (const float*)d_in[3];
    const float* emb     = (const float*)d_in[4];
    const float* w2      = (const float*)d_in[5];
    const float* b2      = (const float*)d_in[6];
    float* out = (float*)d_out;

    char* ws = (char*)d_ws;
    unsigned short* hbf = (unsigned short*)ws;              // 512 KB (HWC)
    int*   offsets      = (int*)(ws + (1 << 20));           // 217 ints
    int*   sorted       = (int*)(ws + (1 << 20) + 4096);    // 4096 ints

    prep_kernel<<<257, 256, 0, stream>>>(x, w1, b1, buckets, hbf, offsets, sorted);
    dyn_kernel<<<NTYPES, 512, 0, stream>>>(hbf, emb, w2, b2, x, offsets, sorted, out);
}